// Round 12
// baseline (328.183 us; speedup 1.0000x reference)
//
#include <hip/hip_runtime.h>
#include <hip/hip_bf16.h>

typedef __attribute__((ext_vector_type(8))) short bf16x8;
typedef __attribute__((ext_vector_type(4))) float f32x4;

#define K_DIM 64
#define CPITCH 72          // shorts per c-row (144 B rows; R10/R11-proven conflict-free LDS frag reads)
// per 256-col band: hi 256*72 + lo 256*72 + 512 floats (norms|inv) = 37888 shorts = 75776 B
#define BAND_SHORTS 37888
#define BAND_SLOTS  4736   // f32x4 slots (75776/16)

// ---------------- prep_x: bf16 hi/lo planes + row norms ----------------
__global__ __launch_bounds__(256) void rbf_prep_x(
    const float* __restrict__ src, int rows,
    __hip_bfloat16* __restrict__ hi, __hip_bfloat16* __restrict__ lo,
    float* __restrict__ norms)
{
    int row  = blockIdx.x * 4 + (threadIdx.x >> 6);
    int lane = threadIdx.x & 63;
    if (row >= rows) return;

    float v = src[(size_t)row * K_DIM + lane];
    __hip_bfloat16 h = __float2bfloat16(v);
    float hf = __bfloat162float(h);
    __hip_bfloat16 l = __float2bfloat16(v - hf);
    hi[(size_t)row * K_DIM + lane] = h;
    lo[(size_t)row * K_DIM + lane] = l;

    float s = v * v;
    #pragma unroll
    for (int off = 32; off > 0; off >>= 1) s += __shfl_down(s, off, 64);
    if (lane == 0) norms[row] = s;
}

// ---------------- prep_c: per-256-col-band blob -----------------------
// Band b (256 c-rows) at blob[b*37888 .. ) shorts:
//   [0,18432):      hi plane, row r at r*72 (first 64 shorts valid)
//   [18432,36864):  lo plane, same layout
//   [36864,37888):  as float[512]: [0..255]=||c||^2, [256..511]=exp(-2*ls)
__global__ __launch_bounds__(256) void rbf_prep_c(
    const float* __restrict__ src, int rows,
    short* __restrict__ blob, const float* __restrict__ log_sigmas)
{
    int row  = blockIdx.x * 4 + (threadIdx.x >> 6);
    int lane = threadIdx.x & 63;
    if (row >= rows) return;

    float v = src[(size_t)row * K_DIM + lane];
    __hip_bfloat16 h = __float2bfloat16(v);
    float hf = __bfloat162float(h);
    __hip_bfloat16 l = __float2bfloat16(v - hf);

    const int band = row >> 8, r = row & 255;
    short* base = blob + (size_t)band * BAND_SHORTS;
    base[r * CPITCH + lane]         = *(short*)&h;
    base[18432 + r * CPITCH + lane] = *(short*)&l;

    float s = v * v;
    #pragma unroll
    for (int off = 32; off > 0; off >>= 1) s += __shfl_down(s, off, 64);
    if (lane == 0) {
        float* f = (float*)(base + 36864);
        f[r]       = s;
        f[256 + r] = __expf(-2.0f * log_sigmas[row]);
    }
}

// ---------------- main: 512(M) x 256(N) tile, byte-minimal ----------------
// R11 CONFIRMED the per-CU vmem-port byte model: time ~ total(load+store)
// bytes / ~6.4 TB/s aggregate. R11 (215 MB loads + 268 MB stores) ran ~85 µs
// on-model. This round only shrinks load bytes: Mt 256->512, Nt 128->256.
// Per block: x-frags 128 KB (regs) + c-band 74 KB (LDS) per 512 KB stored;
// 512 blocks -> loads 103 MB, T = 371 MB -> ~58-70 µs predicted.
// Machinery unchanged from R11 (all verified): pitch-72 LDS c-frags, single
// barrier, stores-only post-barrier vmem stream, nt f32x4 stores,
// orientation A=centres/B=x (D: col(lane&15)=M row, row(quad*4+reg)=N col).
// 512 thr = 8 waves, wave owns 64 M-rows (same 64 VGPR x-frag budget as R11).
// LDS 75776 B -> 2 blocks/CU (grid 512 = exactly 2/CU).
__global__ __launch_bounds__(512, 2) void rbf_main(
    const __hip_bfloat16* __restrict__ xhi, const __hip_bfloat16* __restrict__ xlo,
    const short* __restrict__ blob, const float* __restrict__ nx,
    float* __restrict__ out, int N)
{
    __shared__ __align__(16) short cs[BAND_SHORTS];   // 75776 B

    const int tid  = threadIdx.x;
    const int wave = tid >> 6;
    const int lane = tid & 63;
    const int quad = lane >> 4;
    const int l16  = lane & 15;

    const int band   = blockIdx.x;        // 0..N/256-1
    const int m_base = blockIdx.y << 9;   // 512 rows per block
    const int n_base = band << 8;         // 256 cols

    // Stage the c-band blob: 4736 f32x4 slots, tid-linear (fully coalesced).
    {
        const f32x4* src = (const f32x4*)(blob + (size_t)band * BAND_SHORTS);
        f32x4* dst = (f32x4*)cs;
        #pragma unroll
        for (int i = 0; i < 10; ++i) {
            const int idx = tid + (i << 9);
            if (idx < BAND_SLOTS) dst[idx] = src[idx];
        }
    }

    // x-fragments for this wave's 64 rows (pre-barrier; only other loads).
    const int wbase = m_base + (wave << 6);
    bf16x8 xh0[4], xh1[4], xl0[4], xl1[4];
    float  nxm[4];
    #pragma unroll
    for (int mg = 0; mg < 4; ++mg) {
        const int xr = wbase + (mg << 4) + l16;
        const size_t ro = (size_t)xr * K_DIM + (quad << 3);
        xh0[mg] = *(const bf16x8*)(xhi + ro);
        xh1[mg] = *(const bf16x8*)(xhi + ro + 32);
        xl0[mg] = *(const bf16x8*)(xlo + ro);
        xl1[mg] = *(const bf16x8*)(xlo + ro + 32);
        nxm[mg] = nx[xr];
    }

    __syncthreads();

    const short* hbase = cs;
    const short* lbase = cs + 18432;
    const float* fbase = (const float*)(cs + 36864);

    for (int ng = 0; ng < 16; ++ng) {
        const int off = ((ng << 4) + l16) * CPITCH + (quad << 3);
        const bf16x8 ch0 = *(const bf16x8*)(hbase + off);
        const bf16x8 ch1 = *(const bf16x8*)(hbase + off + 32);
        const bf16x8 cl0 = *(const bf16x8*)(lbase + off);
        const bf16x8 cl1 = *(const bf16x8*)(lbase + off + 32);

        const int jc = (ng << 4) + (quad << 2);       // band-local col of 4 outputs
        const f32x4 nc4 = *(const f32x4*)&fbase[jc];
        const f32x4 iv4 = *(const f32x4*)&fbase[256 + jc];

        #pragma unroll
        for (int mg = 0; mg < 4; ++mg) {
            f32x4 acc = {0.f, 0.f, 0.f, 0.f};
            acc = __builtin_amdgcn_mfma_f32_16x16x32_bf16(ch0, xh0[mg], acc, 0, 0, 0);
            acc = __builtin_amdgcn_mfma_f32_16x16x32_bf16(ch1, xh1[mg], acc, 0, 0, 0);
            acc = __builtin_amdgcn_mfma_f32_16x16x32_bf16(ch0, xl0[mg], acc, 0, 0, 0);
            acc = __builtin_amdgcn_mfma_f32_16x16x32_bf16(ch1, xl1[mg], acc, 0, 0, 0);
            acc = __builtin_amdgcn_mfma_f32_16x16x32_bf16(cl0, xh0[mg], acc, 0, 0, 0);
            acc = __builtin_amdgcn_mfma_f32_16x16x32_bf16(cl1, xh1[mg], acc, 0, 0, 0);

            f32x4 res;
            #pragma unroll
            for (int r = 0; r < 4; ++r) {
                float sq = fmaxf(nxm[mg] + nc4[r] - 2.0f * acc[r], 0.f);
                res[r] = __expf(-sq * iv4[r]);
            }
            __builtin_nontemporal_store(
                res, (f32x4*)(out + (size_t)(wbase + (mg << 4) + l16) * N + n_base + jc));
        }
    }
}

// ---------------- fallback: fully fused (R2's passing kernel) ----------------
__device__ __forceinline__ void split8(const float* __restrict__ p,
                                       bf16x8& hi, bf16x8& lo, float& ss) {
    #pragma unroll
    for (int j = 0; j < 8; ++j) {
        float v = p[j];
        ss = fmaf(v, v, ss);
        __hip_bfloat16 h = __float2bfloat16(v);
        float hf = __bfloat162float(h);
        __hip_bfloat16 l = __float2bfloat16(v - hf);
        hi[j] = *reinterpret_cast<const short*>(&h);
        lo[j] = *reinterpret_cast<const short*>(&l);
    }
}

__global__ __launch_bounds__(256) void rbf_fused(
    const float* __restrict__ x, const float* __restrict__ c,
    const float* __restrict__ ls, float* __restrict__ out, int N)
{
    const int wave = threadIdx.x >> 6;
    const int lane = threadIdx.x & 63;
    const int quad = lane >> 4;
    const int l16  = lane & 15;

    const int m_base = (blockIdx.y << 6) + (wave << 4);
    const int n_base = blockIdx.x << 6;

    const int am = m_base + l16;
    const float* xp = x + (size_t)am * K_DIM;
    bf16x8 ahi0, alo0, ahi1, alo1;
    float ssx = 0.f;
    split8(xp + quad * 8,      ahi0, alo0, ssx);
    split8(xp + 32 + quad * 8, ahi1, alo1, ssx);
    ssx += __shfl_xor(ssx, 16, 64);
    ssx += __shfl_xor(ssx, 32, 64);
    float nxr[4];
    #pragma unroll
    for (int r = 0; r < 4; ++r) nxr[r] = __shfl(ssx, quad * 4 + r, 64);

    #pragma unroll
    for (int nt = 0; nt < 4; ++nt) {
        const int n = n_base + nt * 16 + l16;
        const float* cp = c + (size_t)n * K_DIM;
        bf16x8 bhi0, blo0, bhi1, blo1;
        float ssc = 0.f;
        split8(cp + quad * 8,      bhi0, blo0, ssc);
        split8(cp + 32 + quad * 8, bhi1, blo1, ssc);
        ssc += __shfl_xor(ssc, 16, 64);
        ssc += __shfl_xor(ssc, 32, 64);

        f32x4 acc = {0.f, 0.f, 0.f, 0.f};
        acc = __builtin_amdgcn_mfma_f32_16x16x32_bf16(ahi0, bhi0, acc, 0, 0, 0);
        acc = __builtin_amdgcn_mfma_f32_16x16x32_bf16(ahi1, bhi1, acc, 0, 0, 0);
        acc = __builtin_amdgcn_mfma_f32_16x16x32_bf16(ahi0, blo0, acc, 0, 0, 0);
        acc = __builtin_amdgcn_mfma_f32_16x16x32_bf16(ahi1, blo1, acc, 0, 0, 0);
        acc = __builtin_amdgcn_mfma_f32_16x16x32_bf16(alo0, bhi0, acc, 0, 0, 0);
        acc = __builtin_amdgcn_mfma_f32_16x16x32_bf16(alo1, bhi1, acc, 0, 0, 0);

        const float invv = __expf(-2.0f * ls[n]);
        #pragma unroll
        for (int r = 0; r < 4; ++r) {
            const int row = m_base + quad * 4 + r;
            float sq = fmaxf(nxr[r] + ssc - 2.0f * acc[r], 0.f);
            out[(size_t)row * N + n] = __expf(-sq * invv);
        }
    }
}

extern "C" void kernel_launch(void* const* d_in, const int* in_sizes, int n_in,
                              void* d_out, int out_size, void* d_ws, size_t ws_size,
                              hipStream_t stream) {
    const float* x  = (const float*)d_in[0];   // [M,64]
    const float* c  = (const float*)d_in[1];   // [N,64]
    const float* ls = (const float*)d_in[2];   // [N]
    float* out = (float*)d_out;                // [M,N]

    const int M = in_sizes[0] / K_DIM;   // 16384
    const int N = in_sizes[2];           // 4096

    size_t off = 0;
    auto place = [&](size_t bytes) { size_t p = off; off += (bytes + 255) & ~(size_t)255; return p; };
    size_t o_xhi  = place((size_t)M * K_DIM * 2);
    size_t o_xlo  = place((size_t)M * K_DIM * 2);
    size_t o_blob = place((size_t)(N / 256) * BAND_SHORTS * 2);
    size_t o_nx   = place((size_t)M * 4);

    if (ws_size >= off && (M % 512) == 0 && (N % 256) == 0) {
        char* ws = (char*)d_ws;
        __hip_bfloat16* xhi = (__hip_bfloat16*)(ws + o_xhi);
        __hip_bfloat16* xlo = (__hip_bfloat16*)(ws + o_xlo);
        short* blob = (short*)(ws + o_blob);
        float* nx   = (float*)(ws + o_nx);

        rbf_prep_x<<<dim3((M + 3) / 4), 256, 0, stream>>>(x, M, xhi, xlo, nx);
        rbf_prep_c<<<dim3((N + 3) / 4), 256, 0, stream>>>(c, N, blob, ls);
        rbf_main<<<dim3(N / 256, M / 512), 512, 0, stream>>>(xhi, xlo, blob, nx, out, N);
    } else {
        rbf_fused<<<dim3(N / 64, M / 64), 256, 0, stream>>>(x, c, ls, out, N);
    }
}

// Round 13
// 307.240 us; speedup vs baseline: 1.0682x; 1.0682x over previous
//
#include <hip/hip_runtime.h>
#include <hip/hip_bf16.h>

typedef __attribute__((ext_vector_type(8))) short bf16x8;
typedef __attribute__((ext_vector_type(4))) float f32x4;

#define K_DIM 64
#define CPITCH 72          // shorts per c-row (144 B; R10-R12-proven conflict-free LDS frag reads)
// per 256-col band: hi 256*72 + lo 256*72 + 512 floats (norms|inv) = 37888 shorts = 75776 B
#define BAND_SHORTS 37888
#define BAND_SLOTS  4736   // f32x4 slots

// ---------------- prep_x: bf16 hi/lo planes + row norms ----------------
__global__ __launch_bounds__(256) void rbf_prep_x(
    const float* __restrict__ src, int rows,
    __hip_bfloat16* __restrict__ hi, __hip_bfloat16* __restrict__ lo,
    float* __restrict__ norms)
{
    int row  = blockIdx.x * 4 + (threadIdx.x >> 6);
    int lane = threadIdx.x & 63;
    if (row >= rows) return;

    float v = src[(size_t)row * K_DIM + lane];
    __hip_bfloat16 h = __float2bfloat16(v);
    float hf = __bfloat162float(h);
    __hip_bfloat16 l = __float2bfloat16(v - hf);
    hi[(size_t)row * K_DIM + lane] = h;
    lo[(size_t)row * K_DIM + lane] = l;

    float s = v * v;
    #pragma unroll
    for (int off = 32; off > 0; off >>= 1) s += __shfl_down(s, off, 64);
    if (lane == 0) norms[row] = s;
}

// ---------------- prep_c: per-256-col-band blob (R12-verified) -------------
//   [0,18432):      hi plane, row r at r*72 (first 64 shorts valid)
//   [18432,36864):  lo plane, same layout
//   [36864,37888):  as float[512]: [0..255]=||c||^2, [256..511]=exp(-2*ls)
__global__ __launch_bounds__(256) void rbf_prep_c(
    const float* __restrict__ src, int rows,
    short* __restrict__ blob, const float* __restrict__ log_sigmas)
{
    int row  = blockIdx.x * 4 + (threadIdx.x >> 6);
    int lane = threadIdx.x & 63;
    if (row >= rows) return;

    float v = src[(size_t)row * K_DIM + lane];
    __hip_bfloat16 h = __float2bfloat16(v);
    float hf = __bfloat162float(h);
    __hip_bfloat16 l = __float2bfloat16(v - hf);

    const int band = row >> 8, r = row & 255;
    short* base = blob + (size_t)band * BAND_SHORTS;
    base[r * CPITCH + lane]         = *(short*)&h;
    base[18432 + r * CPITCH + lane] = *(short*)&l;

    float s = v * v;
    #pragma unroll
    for (int off = 32; off > 0; off >>= 1) s += __shfl_down(s, off, 64);
    if (lane == 0) {
        float* f = (float*)(base + 36864);
        f[r]       = s;
        f[256 + r] = __expf(-2.0f * log_sigmas[row]);
    }
}

// ---------------- main: 256(M) x 256(N), R11 structure + wider band -------
// R11 CONFIRMED the per-CU vmem-port byte model (~6.4 TB/s aggregate
// load+store). R12's 512-thread blocks hit a VGPR occupancy cliff (1
// block/CU, staging latency exposed). This keeps R11's verified shape —
// 256 thr = 4 waves, wave owns 64 M-rows (64 VGPR x-frags), pitch-72 LDS
// c-frags, single barrier, stores-only post-barrier vmem stream — and only
// widens the c-band to 256 cols. LDS 75776 B is the residency limiter at
// exactly 2 blocks/CU (VGPR cap 256 via launch_bounds can't bite at 2
// waves/SIMD); grid 1024 = 4 assignments/CU so next block's staging
// overlaps current block's compute.
// Bytes: loads 145 MB + stores 268 MB = 413 MB -> ~65 µs model.
__global__ __launch_bounds__(256, 2) void rbf_main(
    const __hip_bfloat16* __restrict__ xhi, const __hip_bfloat16* __restrict__ xlo,
    const short* __restrict__ blob, const float* __restrict__ nx,
    float* __restrict__ out, int N)
{
    __shared__ __align__(16) short cs[BAND_SHORTS];   // 75776 B

    const int tid  = threadIdx.x;
    const int wave = tid >> 6;
    const int lane = tid & 63;
    const int quad = lane >> 4;
    const int l16  = lane & 15;

    const int band   = blockIdx.x;        // 0..N/256-1
    const int m_base = blockIdx.y << 8;   // 256 rows per block
    const int n_base = band << 8;         // 256 cols

    // Stage the c-band blob: 4736 f32x4 slots, tid-linear (fully coalesced).
    {
        const f32x4* src = (const f32x4*)(blob + (size_t)band * BAND_SHORTS);
        f32x4* dst = (f32x4*)cs;
        #pragma unroll
        for (int i = 0; i < 19; ++i) {
            const int idx = tid + (i << 8);
            if (idx < BAND_SLOTS) dst[idx] = src[idx];
        }
    }

    // x-fragments for this wave's 64 rows (pre-barrier; only other loads).
    const int wbase = m_base + (wave << 6);
    bf16x8 xh0[4], xh1[4], xl0[4], xl1[4];
    float  nxm[4];
    #pragma unroll
    for (int mg = 0; mg < 4; ++mg) {
        const int xr = wbase + (mg << 4) + l16;
        const size_t ro = (size_t)xr * K_DIM + (quad << 3);
        xh0[mg] = *(const bf16x8*)(xhi + ro);
        xh1[mg] = *(const bf16x8*)(xhi + ro + 32);
        xl0[mg] = *(const bf16x8*)(xlo + ro);
        xl1[mg] = *(const bf16x8*)(xlo + ro + 32);
        nxm[mg] = nx[xr];
    }

    __syncthreads();

    const short* hbase = cs;
    const short* lbase = cs + 18432;
    const float* fbase = (const float*)(cs + 36864);

    for (int ng = 0; ng < 16; ++ng) {
        const int off = ((ng << 4) + l16) * CPITCH + (quad << 3);
        const bf16x8 ch0 = *(const bf16x8*)(hbase + off);
        const bf16x8 ch1 = *(const bf16x8*)(hbase + off + 32);
        const bf16x8 cl0 = *(const bf16x8*)(lbase + off);
        const bf16x8 cl1 = *(const bf16x8*)(lbase + off + 32);

        const int jc = (ng << 4) + (quad << 2);       // band-local col of 4 outputs
        const f32x4 nc4 = *(const f32x4*)&fbase[jc];
        const f32x4 iv4 = *(const f32x4*)&fbase[256 + jc];

        #pragma unroll
        for (int mg = 0; mg < 4; ++mg) {
            f32x4 acc = {0.f, 0.f, 0.f, 0.f};
            acc = __builtin_amdgcn_mfma_f32_16x16x32_bf16(ch0, xh0[mg], acc, 0, 0, 0);
            acc = __builtin_amdgcn_mfma_f32_16x16x32_bf16(ch1, xh1[mg], acc, 0, 0, 0);
            acc = __builtin_amdgcn_mfma_f32_16x16x32_bf16(ch0, xl0[mg], acc, 0, 0, 0);
            acc = __builtin_amdgcn_mfma_f32_16x16x32_bf16(ch1, xl1[mg], acc, 0, 0, 0);
            acc = __builtin_amdgcn_mfma_f32_16x16x32_bf16(cl0, xh0[mg], acc, 0, 0, 0);
            acc = __builtin_amdgcn_mfma_f32_16x16x32_bf16(cl1, xh1[mg], acc, 0, 0, 0);

            f32x4 res;
            #pragma unroll
            for (int r = 0; r < 4; ++r) {
                float sq = fmaxf(nxm[mg] + nc4[r] - 2.0f * acc[r], 0.f);
                res[r] = __expf(-sq * iv4[r]);
            }
            __builtin_nontemporal_store(
                res, (f32x4*)(out + (size_t)(wbase + (mg << 4) + l16) * N + n_base + jc));
        }
    }
}

// ---------------- fallback: fully fused (R2's passing kernel) ----------------
__device__ __forceinline__ void split8(const float* __restrict__ p,
                                       bf16x8& hi, bf16x8& lo, float& ss) {
    #pragma unroll
    for (int j = 0; j < 8; ++j) {
        float v = p[j];
        ss = fmaf(v, v, ss);
        __hip_bfloat16 h = __float2bfloat16(v);
        float hf = __bfloat162float(h);
        __hip_bfloat16 l = __float2bfloat16(v - hf);
        hi[j] = *reinterpret_cast<const short*>(&h);
        lo[j] = *reinterpret_cast<const short*>(&l);
    }
}

__global__ __launch_bounds__(256) void rbf_fused(
    const float* __restrict__ x, const float* __restrict__ c,
    const float* __restrict__ ls, float* __restrict__ out, int N)
{
    const int wave = threadIdx.x >> 6;
    const int lane = threadIdx.x & 63;
    const int quad = lane >> 4;
    const int l16  = lane & 15;

    const int m_base = (blockIdx.y << 6) + (wave << 4);
    const int n_base = blockIdx.x << 6;

    const int am = m_base + l16;
    const float* xp = x + (size_t)am * K_DIM;
    bf16x8 ahi0, alo0, ahi1, alo1;
    float ssx = 0.f;
    split8(xp + quad * 8,      ahi0, alo0, ssx);
    split8(xp + 32 + quad * 8, ahi1, alo1, ssx);
    ssx += __shfl_xor(ssx, 16, 64);
    ssx += __shfl_xor(ssx, 32, 64);
    float nxr[4];
    #pragma unroll
    for (int r = 0; r < 4; ++r) nxr[r] = __shfl(ssx, quad * 4 + r, 64);

    #pragma unroll
    for (int nt = 0; nt < 4; ++nt) {
        const int n = n_base + nt * 16 + l16;
        const float* cp = c + (size_t)n * K_DIM;
        bf16x8 bhi0, blo0, bhi1, blo1;
        float ssc = 0.f;
        split8(cp + quad * 8,      bhi0, blo0, ssc);
        split8(cp + 32 + quad * 8, bhi1, blo1, ssc);
        ssc += __shfl_xor(ssc, 16, 64);
        ssc += __shfl_xor(ssc, 32, 64);

        f32x4 acc = {0.f, 0.f, 0.f, 0.f};
        acc = __builtin_amdgcn_mfma_f32_16x16x32_bf16(ahi0, bhi0, acc, 0, 0, 0);
        acc = __builtin_amdgcn_mfma_f32_16x16x32_bf16(ahi1, bhi1, acc, 0, 0, 0);
        acc = __builtin_amdgcn_mfma_f32_16x16x32_bf16(ahi0, blo0, acc, 0, 0, 0);
        acc = __builtin_amdgcn_mfma_f32_16x16x32_bf16(ahi1, blo1, acc, 0, 0, 0);
        acc = __builtin_amdgcn_mfma_f32_16x16x32_bf16(alo0, bhi0, acc, 0, 0, 0);
        acc = __builtin_amdgcn_mfma_f32_16x16x32_bf16(alo1, bhi1, acc, 0, 0, 0);

        const float invv = __expf(-2.0f * ls[n]);
        #pragma unroll
        for (int r = 0; r < 4; ++r) {
            const int row = m_base + quad * 4 + r;
            float sq = fmaxf(nxr[r] + ssc - 2.0f * acc[r], 0.f);
            out[(size_t)row * N + n] = __expf(-sq * invv);
        }
    }
}

extern "C" void kernel_launch(void* const* d_in, const int* in_sizes, int n_in,
                              void* d_out, int out_size, void* d_ws, size_t ws_size,
                              hipStream_t stream) {
    const float* x  = (const float*)d_in[0];   // [M,64]
    const float* c  = (const float*)d_in[1];   // [N,64]
    const float* ls = (const float*)d_in[2];   // [N]
    float* out = (float*)d_out;                // [M,N]

    const int M = in_sizes[0] / K_DIM;   // 16384
    const int N = in_sizes[2];           // 4096

    size_t off = 0;
    auto place = [&](size_t bytes) { size_t p = off; off += (bytes + 255) & ~(size_t)255; return p; };
    size_t o_xhi  = place((size_t)M * K_DIM * 2);
    size_t o_xlo  = place((size_t)M * K_DIM * 2);
    size_t o_blob = place((size_t)(N / 256) * BAND_SHORTS * 2);
    size_t o_nx   = place((size_t)M * 4);

    if (ws_size >= off && (M % 256) == 0 && (N % 256) == 0) {
        char* ws = (char*)d_ws;
        __hip_bfloat16* xhi = (__hip_bfloat16*)(ws + o_xhi);
        __hip_bfloat16* xlo = (__hip_bfloat16*)(ws + o_xlo);
        short* blob = (short*)(ws + o_blob);
        float* nx   = (float*)(ws + o_nx);

        rbf_prep_x<<<dim3((M + 3) / 4), 256, 0, stream>>>(x, M, xhi, xlo, nx);
        rbf_prep_c<<<dim3((N + 3) / 4), 256, 0, stream>>>(c, N, blob, ls);
        rbf_main<<<dim3(N / 256, M / 256), 256, 0, stream>>>(xhi, xlo, blob, nx, out, N);
    } else {
        rbf_fused<<<dim3(N / 64, M / 64), 256, 0, stream>>>(x, c, ls, out, N);
    }
}